// Round 1
// baseline (1055.467 us; speedup 1.0000x reference)
//
#include <hip/hip_runtime.h>
#include <stdint.h>

#define LQ 2048
#define EDIM 1024
#define HN 8
#define DH 128
#define BATCH 4
#define ATT_SCALE 0.08838834764831845f  // 1/sqrt(128)

typedef short bf16x8 __attribute__((ext_vector_type(8)));
typedef float f32x4 __attribute__((ext_vector_type(4)));
typedef unsigned short u16;
typedef unsigned short u16x4 __attribute__((ext_vector_type(4)));

// round-to-nearest-even f32 -> bf16 (bit pattern)
__device__ __forceinline__ u16 f2bf(float f) {
  union { float f; uint32_t u; } c; c.f = f;
  uint32_t u = c.u;
  return (u16)((u + 0x7fffu + ((u >> 16) & 1u)) >> 16);
}

// async global->LDS, 16B per lane. LDS dest must be wave-uniform base + lane*16.
__device__ __forceinline__ void async16(const void* g, void* l) {
  __builtin_amdgcn_global_load_lds((const __attribute__((address_space(1))) void*)g,
                                   (__attribute__((address_space(3))) void*)l, 16, 0, 0);
}

// ---------------- fp32 -> bf16 elementwise (qInputs / kvInputs) ----------------
__global__ __launch_bounds__(256) void cvt_kernel(const float* __restrict__ xq,
                                                  const float* __restrict__ xkv,
                                                  u16* __restrict__ oq, u16* __restrict__ okv) {
  const float* in = blockIdx.y ? xkv : xq;
  u16* out = blockIdx.y ? okv : oq;
  size_t i = (size_t)blockIdx.x * 256 + threadIdx.x;
  float4 v = ((const float4*)in)[i];
  u16x4 o;
  o.x = f2bf(v.x); o.y = f2bf(v.y); o.z = f2bf(v.z); o.w = f2bf(v.w);
  ((u16x4*)out)[i] = o;
}

// ---------------- tiled transpose + cvt for the 4 weight matrices ----------------
// out[n][k] = bf16(in[k][n]), 1024x1024
__global__ __launch_bounds__(256) void transpose_cvt(const float* __restrict__ w0, const float* __restrict__ w1,
                                                     const float* __restrict__ w2, const float* __restrict__ w3,
                                                     u16* __restrict__ o0, u16* __restrict__ o1,
                                                     u16* __restrict__ o2, u16* __restrict__ o3) {
  const float* in; u16* out;
  switch (blockIdx.z) {
    case 0: in = w0; out = o0; break;
    case 1: in = w1; out = o1; break;
    case 2: in = w2; out = o2; break;
    default: in = w3; out = o3; break;
  }
  __shared__ float tile[32][33];
  int tx = threadIdx.x, ty = threadIdx.y;
  int x0 = blockIdx.x * 32;   // input col (n)
  int y0 = blockIdx.y * 32;   // input row (k)
#pragma unroll
  for (int j = 0; j < 32; j += 8)
    tile[ty + j][tx] = in[(size_t)(y0 + ty + j) * EDIM + x0 + tx];
  __syncthreads();
#pragma unroll
  for (int j = 0; j < 32; j += 8)
    out[(size_t)(x0 + ty + j) * EDIM + (y0 + tx)] = f2bf(tile[tx][ty + j]);
}

// ---------------- bf16 GEMM: C[M x 1024] = A[M x 1024] @ Bt[n][k]^T ----------------
// 128x128 tile, BK=32, 16x16x32 MFMA, global_load_lds width 16 (m97 structure).
// MODE 0: store bf16 row-major [M][1024]
// MODE 1: store bf16 transposed for V: addr = ((b*1024 + n) * 2048 + l), b=gm>>11, l=gm&2047
// MODE 2: store fp32 row-major (final output)
template <int MODE>
__global__ __launch_bounds__(256) void gemm_bt(const u16* __restrict__ A, const u16* __restrict__ Bt,
                                               void* __restrict__ C) {
  __shared__ __align__(16) u16 As[128 * 32];
  __shared__ __align__(16) u16 Bs[128 * 32];
  const int tid = threadIdx.x;
  const int l = tid & 63;
  const int w = tid >> 6;
  const int m0 = blockIdx.x * 128;
  const int n0 = blockIdx.y * 128;
  const int wm = (w >> 1) * 64;
  const int wn = (w & 1) * 64;
  const int lrow = l >> 2;        // staging: row within 16-row issue
  const int lk8 = (l & 3) * 8;    // staging: k element offset
  const int fm = l & 15;          // frag: m/n index
  const int fk = (l >> 4) * 8;    // frag: k element offset
  f32x4 acc[4][4] = {};
  for (int k0 = 0; k0 < EDIM; k0 += 32) {
    __syncthreads();
#pragma unroll
    for (int ii = 0; ii < 2; ++ii) {
      int i = w * 2 + ii;
      async16(A + (size_t)(m0 + i * 16 + lrow) * EDIM + k0 + lk8, &As[i * 512 + l * 8]);
      async16(Bt + (size_t)(n0 + i * 16 + lrow) * EDIM + k0 + lk8, &Bs[i * 512 + l * 8]);
    }
    __syncthreads();
    bf16x8 a[4], b[4];
#pragma unroll
    for (int i = 0; i < 4; ++i) a[i] = *(const bf16x8*)&As[(wm + i * 16 + fm) * 32 + fk];
#pragma unroll
    for (int j = 0; j < 4; ++j) b[j] = *(const bf16x8*)&Bs[(wn + j * 16 + fm) * 32 + fk];
#pragma unroll
    for (int i = 0; i < 4; ++i)
#pragma unroll
      for (int j = 0; j < 4; ++j)
        acc[i][j] = __builtin_amdgcn_mfma_f32_16x16x32_bf16(a[i], b[j], acc[i][j], 0, 0, 0);
  }
  const int rr = (l >> 4) * 4;
#pragma unroll
  for (int i = 0; i < 4; ++i)
#pragma unroll
    for (int j = 0; j < 4; ++j)
#pragma unroll
      for (int r = 0; r < 4; ++r) {
        int gm = m0 + wm + i * 16 + rr + r;
        int gn = n0 + wn + j * 16 + fm;
        float v = acc[i][j][r];
        if (MODE == 0) {
          ((u16*)C)[(size_t)gm * EDIM + gn] = f2bf(v);
        } else if (MODE == 1) {
          ((u16*)C)[((size_t)(gm >> 11) * EDIM + gn) * LQ + (gm & 2047)] = f2bf(v);
        } else {
          ((float*)C)[(size_t)gm * EDIM + gn] = v;
        }
      }
}

// ---------------- flash attention ----------------
// grid (qtile=16, h=8, b=4); 4 waves x 32 q-rows; BN=128 keys/iter.
// Qb,Kb: bf16 [b*2048+l][h*128+d]; Vt: bf16 [(b*8+h)*128+d][l]; ctx: bf16 [b*2048+l][h*128+d]
__global__ __launch_bounds__(256, 2) void attn_kernel(const u16* __restrict__ Qb, const u16* __restrict__ Kb,
                                                      const u16* __restrict__ Vt,
                                                      const unsigned char* __restrict__ mask,
                                                      u16* __restrict__ ctx) {
  __shared__ __align__(16) u16 KV[128 * 128];   // K tile, then V tile (reused)
  __shared__ __align__(16) u16 P[128 * 136];    // P in A-layout, padded stride 136
  const int tid = threadIdx.x;
  const int l = tid & 63;
  const int w = tid >> 6;
  const int qt = blockIdx.x;
  const int h = blockIdx.y;
  const int b = blockIdx.z;
  const int fm = l & 15;
  const int q4 = l >> 4;
  const int fk = q4 * 8;
  const int qbase = qt * 128 + w * 32;  // q row (within sequence) base for this wave

  // Q fragments: A-layout, lane holds Q[m=fm][k=q4*8+j]
  bf16x8 qf[2][4];
#pragma unroll
  for (int mt = 0; mt < 2; ++mt)
#pragma unroll
    for (int ks = 0; ks < 4; ++ks)
      qf[mt][ks] = *(const bf16x8*)(Qb + (size_t)(b * LQ + qbase + mt * 16 + fm) * EDIM + h * DH + ks * 32 + fk);

  float mst[2][4], lst[2][4];
  f32x4 o[2][8] = {};
#pragma unroll
  for (int mt = 0; mt < 2; ++mt)
#pragma unroll
    for (int r = 0; r < 4; ++r) { mst[mt][r] = -1e30f; lst[mt][r] = 0.f; }

  const size_t mbase = (size_t)(b * HN + h) * (size_t)LQ * LQ;

  for (int kt = 0; kt < 16; ++kt) {
    __syncthreads();  // previous iter's V/P reads done before restaging K
    // stage K tile [n][d] (rows of Kb for this head)
#pragma unroll
    for (int ii = 0; ii < 8; ++ii) {
      int r = w * 32 + ii * 4 + q4;
      async16(Kb + (size_t)(b * LQ + kt * 128 + r) * EDIM + h * DH + fm * 8,
              &KV[(w * 32 + ii * 4) * 128 + l * 8]);
    }
    __syncthreads();  // K resident
    // S = Q K^T
    f32x4 s[2][8] = {};
#pragma unroll
    for (int ks = 0; ks < 4; ++ks)
#pragma unroll
      for (int nt = 0; nt < 8; ++nt) {
        bf16x8 kf = *(const bf16x8*)&KV[(nt * 16 + fm) * 128 + ks * 32 + fk];
        s[0][nt] = __builtin_amdgcn_mfma_f32_16x16x32_bf16(qf[0][ks], kf, s[0][nt], 0, 0, 0);
        s[1][nt] = __builtin_amdgcn_mfma_f32_16x16x32_bf16(qf[1][ks], kf, s[1][nt], 0, 0, 0);
      }
    // scale + mask (reference: where(mask, -1e9, scores*scale))
#pragma unroll
    for (int mt = 0; mt < 2; ++mt)
#pragma unroll
      for (int r = 0; r < 4; ++r) {
        int qr = qbase + mt * 16 + q4 * 4 + r;
        const unsigned char* mrow = mask + mbase + (size_t)qr * LQ + kt * 128 + fm;
#pragma unroll
        for (int nt = 0; nt < 8; ++nt) {
          float v = s[mt][nt][r] * ATT_SCALE;
          s[mt][nt][r] = mrow[nt * 16] ? -1e9f : v;
        }
      }
    // online softmax (row = over 128 cols: 8 local + 16-lane butterfly)
#pragma unroll
    for (int mt = 0; mt < 2; ++mt)
#pragma unroll
      for (int r = 0; r < 4; ++r) {
        float mx = s[mt][0][r];
#pragma unroll
        for (int nt = 1; nt < 8; ++nt) mx = fmaxf(mx, s[mt][nt][r]);
#pragma unroll
        for (int off = 1; off < 16; off <<= 1) mx = fmaxf(mx, __shfl_xor(mx, off));
        float mnew = fmaxf(mst[mt][r], mx);
        float alpha = __expf(mst[mt][r] - mnew);
        float sum = 0.f;
#pragma unroll
        for (int nt = 0; nt < 8; ++nt) {
          float p = __expf(s[mt][nt][r] - mnew);
          s[mt][nt][r] = p;
          sum += p;
        }
#pragma unroll
        for (int off = 1; off < 16; off <<= 1) sum += __shfl_xor(sum, off);
        mst[mt][r] = mnew;
        lst[mt][r] = lst[mt][r] * alpha + sum;
#pragma unroll
        for (int dt = 0; dt < 8; ++dt) o[mt][dt][r] *= alpha;
      }
    __syncthreads();  // all waves done reading K tile
    // stage V^T tile [d][n] into KV; write P (bf16) to LDS
#pragma unroll
    for (int ii = 0; ii < 8; ++ii) {
      int d = w * 32 + ii * 4 + q4;
      async16(Vt + ((size_t)(b * HN + h) * DH + d) * LQ + kt * 128 + fm * 8,
              &KV[(w * 32 + ii * 4) * 128 + l * 8]);
    }
#pragma unroll
    for (int mt = 0; mt < 2; ++mt)
#pragma unroll
      for (int r = 0; r < 4; ++r)
#pragma unroll
        for (int nt = 0; nt < 8; ++nt)
          P[(w * 32 + mt * 16 + q4 * 4 + r) * 136 + nt * 16 + fm] = f2bf(s[mt][nt][r]);
    __syncthreads();  // V resident + P visible
    // O += P V
#pragma unroll
    for (int ns = 0; ns < 4; ++ns) {
      bf16x8 pf0 = *(const bf16x8*)&P[(w * 32 + fm) * 136 + ns * 32 + fk];
      bf16x8 pf1 = *(const bf16x8*)&P[(w * 32 + 16 + fm) * 136 + ns * 32 + fk];
#pragma unroll
      for (int dt = 0; dt < 8; ++dt) {
        bf16x8 vf = *(const bf16x8*)&KV[(dt * 16 + fm) * 128 + ns * 32 + fk];
        o[0][dt] = __builtin_amdgcn_mfma_f32_16x16x32_bf16(pf0, vf, o[0][dt], 0, 0, 0);
        o[1][dt] = __builtin_amdgcn_mfma_f32_16x16x32_bf16(pf1, vf, o[1][dt], 0, 0, 0);
      }
    }
  }
  // epilogue: ctx = O / l
#pragma unroll
  for (int mt = 0; mt < 2; ++mt)
#pragma unroll
    for (int r = 0; r < 4; ++r) {
      float inv = 1.f / lst[mt][r];
      int gq = b * LQ + qbase + mt * 16 + q4 * 4 + r;
#pragma unroll
      for (int dt = 0; dt < 8; ++dt)
        ctx[(size_t)gq * EDIM + h * DH + dt * 16 + fm] = f2bf(o[mt][dt][r] * inv);
    }
}

extern "C" void kernel_launch(void* const* d_in, const int* in_sizes, int n_in,
                              void* d_out, int out_size, void* d_ws, size_t ws_size,
                              hipStream_t stream) {
  const float* qIn = (const float*)d_in[0];
  const float* kvIn = (const float*)d_in[1];
  const unsigned char* mask = (const unsigned char*)d_in[2];
  const float* W_Q = (const float*)d_in[3];
  const float* W_K = (const float*)d_in[4];
  const float* W_V = (const float*)d_in[5];
  const float* W_fc = (const float*)d_in[6];
  float* out = (float*)d_out;

  uint8_t* ws = (uint8_t*)d_ws;
  const size_t MB = 1u << 20;
  u16* xq   = (u16*)(ws);             // 16 MB
  u16* xkv  = (u16*)(ws + 16 * MB);   // 16 MB
  u16* WqT  = (u16*)(ws + 32 * MB);   // 2 MB
  u16* WkT  = (u16*)(ws + 34 * MB);   // 2 MB
  u16* WvT  = (u16*)(ws + 36 * MB);   // 2 MB
  u16* WfcT = (u16*)(ws + 38 * MB);   // 2 MB
  u16* Qb   = (u16*)(ws + 40 * MB);   // 16 MB
  u16* Kb   = (u16*)(ws + 56 * MB);   // 16 MB
  u16* Vt   = (u16*)(ws + 72 * MB);   // 16 MB
  u16* ctx  = (u16*)(ws + 88 * MB);   // 16 MB -> 104 MB total

  cvt_kernel<<<dim3(8192, 2), 256, 0, stream>>>(qIn, kvIn, xq, xkv);
  transpose_cvt<<<dim3(32, 32, 4), dim3(32, 8), 0, stream>>>(W_Q, W_K, W_V, W_fc, WqT, WkT, WvT, WfcT);
  gemm_bt<0><<<dim3(64, 8), 256, 0, stream>>>(xq, WqT, Qb);
  gemm_bt<0><<<dim3(64, 8), 256, 0, stream>>>(xkv, WkT, Kb);
  gemm_bt<1><<<dim3(64, 8), 256, 0, stream>>>(xkv, WvT, Vt);
  attn_kernel<<<dim3(16, 8, 4), 256, 0, stream>>>(Qb, Kb, Vt, mask, ctx);
  gemm_bt<2><<<dim3(64, 8), 256, 0, stream>>>(ctx, WfcT, out);
}

// Round 2
// 924.863 us; speedup vs baseline: 1.1412x; 1.1412x over previous
//
#include <hip/hip_runtime.h>
#include <stdint.h>

#define LQ 2048
#define EDIM 1024
#define HN 8
#define DH 128
#define BATCH 4
#define ATT_SCALE 0.08838834764831845f  // 1/sqrt(128)

typedef short bf16x8 __attribute__((ext_vector_type(8)));
typedef float f32x4 __attribute__((ext_vector_type(4)));
typedef unsigned short u16;
typedef unsigned short u16x4 __attribute__((ext_vector_type(4)));

// round-to-nearest-even f32 -> bf16 (bit pattern)
__device__ __forceinline__ u16 f2bf(float f) {
  union { float f; uint32_t u; } c; c.f = f;
  uint32_t u = c.u;
  return (u16)((u + 0x7fffu + ((u >> 16) & 1u)) >> 16);
}

// async global->LDS, 16B per lane. LDS dest must be wave-uniform base + lane*16.
__device__ __forceinline__ void async16(const void* g, void* l) {
  __builtin_amdgcn_global_load_lds((const __attribute__((address_space(1))) void*)g,
                                   (__attribute__((address_space(3))) void*)l, 16, 0, 0);
}

// ---------------- fp32 -> bf16 elementwise (qInputs / kvInputs) ----------------
__global__ __launch_bounds__(256) void cvt_kernel(const float* __restrict__ xq,
                                                  const float* __restrict__ xkv,
                                                  u16* __restrict__ oq, u16* __restrict__ okv) {
  const float* in = blockIdx.y ? xkv : xq;
  u16* out = blockIdx.y ? okv : oq;
  size_t i = (size_t)blockIdx.x * 256 + threadIdx.x;
  float4 v = ((const float4*)in)[i];
  u16x4 o;
  o.x = f2bf(v.x); o.y = f2bf(v.y); o.z = f2bf(v.z); o.w = f2bf(v.w);
  ((u16x4*)out)[i] = o;
}

// ---------------- tiled transpose + cvt for the 4 weight matrices ----------------
// out[n][k] = bf16(in[k][n]), 1024x1024
__global__ __launch_bounds__(256) void transpose_cvt(const float* __restrict__ w0, const float* __restrict__ w1,
                                                     const float* __restrict__ w2, const float* __restrict__ w3,
                                                     u16* __restrict__ o0, u16* __restrict__ o1,
                                                     u16* __restrict__ o2, u16* __restrict__ o3) {
  const float* in; u16* out;
  switch (blockIdx.z) {
    case 0: in = w0; out = o0; break;
    case 1: in = w1; out = o1; break;
    case 2: in = w2; out = o2; break;
    default: in = w3; out = o3; break;
  }
  __shared__ float tile[32][33];
  int tx = threadIdx.x, ty = threadIdx.y;
  int x0 = blockIdx.x * 32;   // input col (n)
  int y0 = blockIdx.y * 32;   // input row (k)
#pragma unroll
  for (int j = 0; j < 32; j += 8)
    tile[ty + j][tx] = in[(size_t)(y0 + ty + j) * EDIM + x0 + tx];
  __syncthreads();
#pragma unroll
  for (int j = 0; j < 32; j += 8)
    out[(size_t)(x0 + ty + j) * EDIM + (y0 + tx)] = f2bf(tile[tx][ty + j]);
}

// ---------------- bf16 GEMM: C[M x N] = A[M x 1024] @ Bt[N x 1024]^T ----------------
// 128x128 tile, BK=32, 16x16x32 MFMA, global_load_lds width 16 (m97 structure).
// MODE 0: store bf16 row-major [M][1024]  (N=1024)
// MODE 1: V^T path: A=WvT (M=1024 dims), Bt=xkv (N=8192 rows). C[d][b*2048+l]
//         store Vt[(b*1024 + d)*2048 + l]  -- contiguous in l.
// MODE 2: store fp32 row-major [M][1024] (final output)
template <int MODE>
__global__ __launch_bounds__(256) void gemm_bt(const u16* __restrict__ A, const u16* __restrict__ Bt,
                                               void* __restrict__ C) {
  __shared__ __align__(16) u16 As[128 * 32];
  __shared__ __align__(16) u16 Bs[128 * 32];
  const int tid = threadIdx.x;
  const int l = tid & 63;
  const int w = tid >> 6;
  const int m0 = blockIdx.x * 128;
  const int n0 = blockIdx.y * 128;
  const int wm = (w >> 1) * 64;
  const int wn = (w & 1) * 64;
  const int lrow = l >> 2;        // staging: row within 16-row issue
  const int lk8 = (l & 3) * 8;    // staging: k element offset
  const int fm = l & 15;          // frag: m/n index
  const int fk = (l >> 4) * 8;    // frag: k element offset
  f32x4 acc[4][4] = {};
  for (int k0 = 0; k0 < EDIM; k0 += 32) {
    __syncthreads();
#pragma unroll
    for (int ii = 0; ii < 2; ++ii) {
      int i = w * 2 + ii;
      async16(A + (size_t)(m0 + i * 16 + lrow) * EDIM + k0 + lk8, &As[i * 512 + l * 8]);
      async16(Bt + (size_t)(n0 + i * 16 + lrow) * EDIM + k0 + lk8, &Bs[i * 512 + l * 8]);
    }
    __syncthreads();
    bf16x8 a[4], b[4];
#pragma unroll
    for (int i = 0; i < 4; ++i) a[i] = *(const bf16x8*)&As[(wm + i * 16 + fm) * 32 + fk];
#pragma unroll
    for (int j = 0; j < 4; ++j) b[j] = *(const bf16x8*)&Bs[(wn + j * 16 + fm) * 32 + fk];
#pragma unroll
    for (int i = 0; i < 4; ++i)
#pragma unroll
      for (int j = 0; j < 4; ++j)
        acc[i][j] = __builtin_amdgcn_mfma_f32_16x16x32_bf16(a[i], b[j], acc[i][j], 0, 0, 0);
  }
  const int rr = (l >> 4) * 4;
#pragma unroll
  for (int i = 0; i < 4; ++i)
#pragma unroll
    for (int j = 0; j < 4; ++j)
#pragma unroll
      for (int r = 0; r < 4; ++r) {
        int gm = m0 + wm + i * 16 + rr + r;
        int gn = n0 + wn + j * 16 + fm;
        float v = acc[i][j][r];
        if (MODE == 0) {
          ((u16*)C)[(size_t)gm * EDIM + gn] = f2bf(v);
        } else if (MODE == 1) {
          ((u16*)C)[((size_t)(gn >> 11) * 1024 + gm) * 2048 + (gn & 2047)] = f2bf(v);
        } else {
          ((float*)C)[(size_t)gm * EDIM + gn] = v;
        }
      }
}

// ---------------- flash attention ----------------
// grid (qtile=16, h=8, b=4); 4 waves x 32 q-rows; BN=128 keys/iter.
// Qb,Kb: bf16 [b*2048+l][h*128+d]; Vt: bf16 [(b*8+h)*128+d][l]; ctx: bf16 [b*2048+l][h*128+d]
// K/V LDS tiles use chunk-XOR swizzle: 16B chunk c of row r stored at chunk c^(r&7).
__global__ __launch_bounds__(256, 2) void attn_kernel(const u16* __restrict__ Qb, const u16* __restrict__ Kb,
                                                      const u16* __restrict__ Vt,
                                                      const unsigned char* __restrict__ mask,
                                                      u16* __restrict__ ctx) {
  __shared__ __align__(16) u16 KV[128 * 128];   // K tile, then V tile (reused)
  __shared__ __align__(16) u16 P[128 * 136];    // P in A-layout, padded stride 136
  const int tid = threadIdx.x;
  const int l = tid & 63;
  const int w = tid >> 6;
  const int qt = blockIdx.x;
  const int h = blockIdx.y;
  const int b = blockIdx.z;
  const int fm = l & 15;
  const int q4 = l >> 4;
  const int fk = q4 * 8;
  const int swz = fm & 7;               // frag-read swizzle (row&7 == fm&7 since rows step by 16)
  const int qbase = qt * 128 + w * 32;  // q row (within sequence) base for this wave

  // Q fragments: A-layout, lane holds Q[m=fm][k=q4*8+j]
  bf16x8 qf[2][4];
#pragma unroll
  for (int mt = 0; mt < 2; ++mt)
#pragma unroll
    for (int ks = 0; ks < 4; ++ks)
      qf[mt][ks] = *(const bf16x8*)(Qb + (size_t)(b * LQ + qbase + mt * 16 + fm) * EDIM + h * DH + ks * 32 + fk);

  float mst[2][4], lst[2][4];
  f32x4 o[2][8] = {};
#pragma unroll
  for (int mt = 0; mt < 2; ++mt)
#pragma unroll
    for (int r = 0; r < 4; ++r) { mst[mt][r] = -1e30f; lst[mt][r] = 0.f; }

  const size_t mbase = (size_t)(b * HN + h) * (size_t)LQ * LQ;

  for (int kt = 0; kt < 16; ++kt) {
    __syncthreads();  // previous iter's V/P reads done before restaging K
    // stage K tile [n][d] with chunk swizzle
#pragma unroll
    for (int ii = 0; ii < 8; ++ii) {
      int rloc = w * 32 + ii * 4 + q4;
      int cs = fm ^ (rloc & 7);
      async16(Kb + (size_t)(b * LQ + kt * 128 + rloc) * EDIM + h * DH + cs * 8,
              &KV[(w * 32 + ii * 4) * 128 + l * 8]);
    }
    __syncthreads();  // K resident

    // mask prefetch (latency hidden under the S MFMAs below)
    unsigned char mreg[2][4][8];
#pragma unroll
    for (int mt = 0; mt < 2; ++mt)
#pragma unroll
      for (int r = 0; r < 4; ++r) {
        int qr = qbase + mt * 16 + q4 * 4 + r;
        const unsigned char* mrow = mask + mbase + (size_t)qr * LQ + kt * 128 + fm;
#pragma unroll
        for (int nt = 0; nt < 8; ++nt) mreg[mt][r][nt] = mrow[nt * 16];
      }

    // S = Q K^T
    f32x4 s[2][8] = {};
#pragma unroll
    for (int ks = 0; ks < 4; ++ks) {
      const int koff = ((ks * 4 + q4) ^ swz) * 8;
#pragma unroll
      for (int nt = 0; nt < 8; ++nt) {
        bf16x8 kf = *(const bf16x8*)&KV[(nt * 16 + fm) * 128 + koff];
        s[0][nt] = __builtin_amdgcn_mfma_f32_16x16x32_bf16(qf[0][ks], kf, s[0][nt], 0, 0, 0);
        s[1][nt] = __builtin_amdgcn_mfma_f32_16x16x32_bf16(qf[1][ks], kf, s[1][nt], 0, 0, 0);
      }
    }
    __syncthreads();  // all waves done reading K tile

    // stage V^T tile [d][n] (async DMA overlaps the softmax VALU below)
#pragma unroll
    for (int ii = 0; ii < 8; ++ii) {
      int dloc = w * 32 + ii * 4 + q4;
      int cs = fm ^ (dloc & 7);
      async16(Vt + ((size_t)(b * HN + h) * DH + dloc) * LQ + kt * 128 + cs * 8,
              &KV[(w * 32 + ii * 4) * 128 + l * 8]);
    }

    // scale + mask + online softmax
#pragma unroll
    for (int mt = 0; mt < 2; ++mt)
#pragma unroll
      for (int r = 0; r < 4; ++r) {
#pragma unroll
        for (int nt = 0; nt < 8; ++nt) {
          float v = s[mt][nt][r] * ATT_SCALE;
          s[mt][nt][r] = mreg[mt][r][nt] ? -1e9f : v;
        }
        float mx = s[mt][0][r];
#pragma unroll
        for (int nt = 1; nt < 8; ++nt) mx = fmaxf(mx, s[mt][nt][r]);
#pragma unroll
        for (int off = 1; off < 16; off <<= 1) mx = fmaxf(mx, __shfl_xor(mx, off));
        float mnew = fmaxf(mst[mt][r], mx);
        float alpha = __expf(mst[mt][r] - mnew);
        float sum = 0.f;
#pragma unroll
        for (int nt = 0; nt < 8; ++nt) {
          float p = __expf(s[mt][nt][r] - mnew);
          s[mt][nt][r] = p;
          sum += p;
        }
#pragma unroll
        for (int off = 1; off < 16; off <<= 1) sum += __shfl_xor(sum, off);
        mst[mt][r] = mnew;
        lst[mt][r] = lst[mt][r] * alpha + sum;
#pragma unroll
        for (int dt = 0; dt < 8; ++dt) o[mt][dt][r] *= alpha;
      }
    // write P (bf16) to LDS (padded stride)
#pragma unroll
    for (int mt = 0; mt < 2; ++mt)
#pragma unroll
      for (int r = 0; r < 4; ++r)
#pragma unroll
        for (int nt = 0; nt < 8; ++nt)
          P[(w * 32 + mt * 16 + q4 * 4 + r) * 136 + nt * 16 + fm] = f2bf(s[mt][nt][r]);
    __syncthreads();  // V resident + P visible

    // O += P V
#pragma unroll
    for (int ns = 0; ns < 4; ++ns) {
      const int voff = ((ns * 4 + q4) ^ swz) * 8;
      bf16x8 pf0 = *(const bf16x8*)&P[(w * 32 + fm) * 136 + ns * 32 + fk];
      bf16x8 pf1 = *(const bf16x8*)&P[(w * 32 + 16 + fm) * 136 + ns * 32 + fk];
#pragma unroll
      for (int dt = 0; dt < 8; ++dt) {
        bf16x8 vf = *(const bf16x8*)&KV[(dt * 16 + fm) * 128 + voff];
        o[0][dt] = __builtin_amdgcn_mfma_f32_16x16x32_bf16(pf0, vf, o[0][dt], 0, 0, 0);
        o[1][dt] = __builtin_amdgcn_mfma_f32_16x16x32_bf16(pf1, vf, o[1][dt], 0, 0, 0);
      }
    }
  }
  // epilogue: ctx = O / l
#pragma unroll
  for (int mt = 0; mt < 2; ++mt)
#pragma unroll
    for (int r = 0; r < 4; ++r) {
      float inv = 1.f / lst[mt][r];
      int gq = b * LQ + qbase + mt * 16 + q4 * 4 + r;
#pragma unroll
      for (int dt = 0; dt < 8; ++dt)
        ctx[(size_t)gq * EDIM + h * DH + dt * 16 + fm] = f2bf(o[mt][dt][r] * inv);
    }
}

extern "C" void kernel_launch(void* const* d_in, const int* in_sizes, int n_in,
                              void* d_out, int out_size, void* d_ws, size_t ws_size,
                              hipStream_t stream) {
  const float* qIn = (const float*)d_in[0];
  const float* kvIn = (const float*)d_in[1];
  const unsigned char* mask = (const unsigned char*)d_in[2];
  const float* W_Q = (const float*)d_in[3];
  const float* W_K = (const float*)d_in[4];
  const float* W_V = (const float*)d_in[5];
  const float* W_fc = (const float*)d_in[6];
  float* out = (float*)d_out;

  uint8_t* ws = (uint8_t*)d_ws;
  const size_t MB = 1u << 20;
  u16* xq   = (u16*)(ws);             // 16 MB
  u16* xkv  = (u16*)(ws + 16 * MB);   // 16 MB
  u16* WqT  = (u16*)(ws + 32 * MB);   // 2 MB
  u16* WkT  = (u16*)(ws + 34 * MB);   // 2 MB
  u16* WvT  = (u16*)(ws + 36 * MB);   // 2 MB
  u16* WfcT = (u16*)(ws + 38 * MB);   // 2 MB
  u16* Qb   = (u16*)(ws + 40 * MB);   // 16 MB
  u16* Kb   = (u16*)(ws + 56 * MB);   // 16 MB
  u16* Vt   = (u16*)(ws + 72 * MB);   // 16 MB
  u16* ctx  = (u16*)(ws + 88 * MB);   // 16 MB -> 104 MB total

  cvt_kernel<<<dim3(8192, 2), 256, 0, stream>>>(qIn, kvIn, xq, xkv);
  transpose_cvt<<<dim3(32, 32, 4), dim3(32, 8), 0, stream>>>(W_Q, W_K, W_V, W_fc, WqT, WkT, WvT, WfcT);
  gemm_bt<0><<<dim3(64, 8), 256, 0, stream>>>(xq, WqT, Qb);
  gemm_bt<0><<<dim3(64, 8), 256, 0, stream>>>(xkv, WkT, Kb);
  gemm_bt<1><<<dim3(8, 64), 256, 0, stream>>>(WvT, xkv, Vt);
  attn_kernel<<<dim3(16, 8, 4), 256, 0, stream>>>(Qb, Kb, Vt, mask, ctx);
  gemm_bt<2><<<dim3(64, 8), 256, 0, stream>>>(ctx, WfcT, out);
}